// Round 12
// baseline (6043.941 us; speedup 1.0000x reference)
//
#include <hip/hip_runtime.h>
#include <math.h>

#define BB 64
#define SS 512
#define DD 207
#define HH 256
#define NWG 64
#define LDW 676   // wgl row stride (%32==4 -> staggered banks)
#define ROW 260   // wrol row stride
#define AG __HIP_MEMORY_SCOPE_AGENT

// ================= v17: v16 with the gen-increment race FIXED ================
// v16's `++gen` was inside `if (tid==0)` -> tids 1..63 never incremented ->
// wait1/wait2 passed instantly -> sync disabled -> absmax fail. Fix: ++gen is
// a standalone statement (all threads) before the tid==0 flag store, exactly
// as in v13/v7. Everything else identical to v16:
//   Phase R: readout-only mini-pass -> xh -> publish x-hat + mask EARLY
//            (stores issued, NO vmcnt yet).
//   Phase G: gh gate pass (same 32 h-rows, L1-hot re-read) — the sc1 drain
//            hides under this compute; then vmcnt(0) + flag (arr1).
// Shortens the period-critical h(t)->x-hat(t) segment ~40% and removes one
// exposed drain from the serial chain.
#define SROWS 672
#define HOFF  416
#define SLOT  (SROWS * 64)
#define BUF_FLOATS ((size_t)SS * SLOT)
#define FLAG_U32 (64 * 32)
#define STAGE_FLOATS ((size_t)SS * DD * 64)
#define WS_NEED6 ((BUF_FLOATS + FLAG_U32 + STAGE_FLOATS) * sizeof(float))

// ---- v3 fallback layout (round-3 proven path) ----
#define V3_AROWS 928
#define V3_HBASE 416
#define V3_ACT (V3_AROWS * 64)
#define V3_FLAGS (64 * 32)
#define V3_WS_SMALL ((size_t)(V3_ACT + V3_FLAGS) * sizeof(float))
#define V3_WS_FULL  ((size_t)(V3_ACT + V3_FLAGS + STAGE_FLOATS) * sizeof(float))

__device__ __forceinline__ void ast4(float* p, float v) {
    union { float f; unsigned u; } c; c.f = v;
    __hip_atomic_store((unsigned*)p, c.u, __ATOMIC_RELAXED, AG);
}

// 12-row (3 gates x unit u) GEMV partial, NORMAL float4 loads (round-3 shape).
// gr0 = global float4-row base (t*672 + local row), wc0 = weight col base.
__device__ __forceinline__ void run_range6(
    const float4* __restrict__ A4, const float* __restrict__ wgl,
    float* __restrict__ red, int u, int bp, int wc0, int gr0, int len, int slot)
{
    float4 c0 = make_float4(0.f, 0.f, 0.f, 0.f);
    float4 c1 = c0, c2 = c0;
    #pragma unroll 4
    for (int k = 0; k < len; k += 4) {
        float4 a0 = A4[(gr0 + k + 0) * 16 + bp];
        float4 a1 = A4[(gr0 + k + 1) * 16 + bp];
        float4 a2 = A4[(gr0 + k + 2) * 16 + bp];
        float4 a3 = A4[(gr0 + k + 3) * 16 + bp];
        float4 w0 = *(const float4*)&wgl[(0 + u) * LDW + wc0 + k];
        float4 w1 = *(const float4*)&wgl[(4 + u) * LDW + wc0 + k];
        float4 w2 = *(const float4*)&wgl[(8 + u) * LDW + wc0 + k];
        c0.x += a0.x*w0.x + a1.x*w0.y + a2.x*w0.z + a3.x*w0.w;
        c0.y += a0.y*w0.x + a1.y*w0.y + a2.y*w0.z + a3.y*w0.w;
        c0.z += a0.z*w0.x + a1.z*w0.y + a2.z*w0.z + a3.z*w0.w;
        c0.w += a0.w*w0.x + a1.w*w0.y + a2.w*w0.z + a3.w*w0.w;
        c1.x += a0.x*w1.x + a1.x*w1.y + a2.x*w1.z + a3.x*w1.w;
        c1.y += a0.y*w1.x + a1.y*w1.y + a2.y*w1.z + a3.y*w1.w;
        c1.z += a0.z*w1.x + a1.z*w1.y + a2.z*w1.z + a3.z*w1.w;
        c1.w += a0.w*w1.x + a1.w*w1.y + a2.w*w1.z + a3.w*w1.w;
        c2.x += a0.x*w2.x + a1.x*w2.y + a2.x*w2.z + a3.x*w2.w;
        c2.y += a0.y*w2.x + a1.y*w2.y + a2.y*w2.z + a3.y*w2.w;
        c2.z += a0.z*w2.x + a1.z*w2.y + a2.z*w2.z + a3.z*w2.w;
        c2.w += a0.w*w2.x + a1.w*w2.y + a2.w*w2.z + a3.w*w2.w;
    }
    float4* R4 = (float4*)red;
    R4[(slot * 12 + 0 + u) * 16 + bp] = c0;
    R4[(slot * 12 + 4 + u) * 16 + bp] = c1;
    R4[(slot * 12 + 8 + u) * 16 + bp] = c2;
}

__global__ __launch_bounds__(256) void rnn_init6(float* __restrict__ ws) {
    int i = blockIdx.x * blockDim.x + threadIdx.x;
    // zero slot-0 h rows (h_0 = 0)
    for (int idx = i; idx < HH * 64; idx += gridDim.x * blockDim.x)
        ws[HOFF * 64 + idx] = 0.f;
    unsigned* fl = (unsigned*)(ws + BUF_FLOATS);
    for (int idx = i; idx < FLAG_U32; idx += gridDim.x * blockDim.x)
        fl[idx] = 0u;
}

__global__ __launch_bounds__(512) void rnn_persist17(
    const float* __restrict__ x, const float* __restrict__ mask,
    const float* __restrict__ W_ih, const float* __restrict__ W_hh,
    const float* __restrict__ b_ih, const float* __restrict__ b_hh,
    const float* __restrict__ W_ro, const float* __restrict__ b_ro,
    float* __restrict__ ws, float* __restrict__ out)
{
    const int wg = blockIdx.x;
    const int tid = threadIdx.x;
    const int lane = tid & 63;
    const int wv = tid >> 6;          // 0..7

    float* buf = ws;
    unsigned* flags = (unsigned*)(ws + BUF_FLOATS);
    float* stage = ws + BUF_FLOATS + FLAG_U32;

    __shared__ float wgl[12 * LDW];      // 12 gate rows x 676 (cols 414/415 = 0)
    __shared__ float wrol[4 * ROW];      // up to 4 readout rows
    __shared__ float red[16 * 12 * 64];  // slots 0-7 xin partials, 8-15 gh
    __shared__ float redB[32 * 64];      // readout partials (8 waves x 4 rows)
    __shared__ float hloc[4 * 64];       // own hidden units
    __shared__ float bihl[12], bhhl[12], brol[4];

    const int d0 = (207 * wg) / NWG;
    const int d1 = (207 * (wg + 1)) / NWG;
    const int dc = d1 - d0;

    for (int i = tid; i < 12 * LDW; i += 512) {
        int r = i / LDW, c = i - r * LDW;
        int rg = (r >> 2) * 256 + wg * 4 + (r & 3);
        float v = 0.f;
        if (c < 414) v = W_ih[rg * 414 + c];
        else if (c >= 416 && c < 672) v = W_hh[rg * 256 + (c - 416)];
        wgl[i] = v;
    }
    for (int i = tid; i < 4 * 256; i += 512) {
        int dl_ = i >> 8, j = i & 255;
        wrol[dl_ * ROW + j] = (dl_ < dc) ? W_ro[(d0 + dl_) * 256 + j] : 0.f;
    }
    if (tid < 12) {
        int rg = (tid >> 2) * 256 + wg * 4 + (tid & 3);
        bihl[tid] = b_ih[rg];
        bhhl[tid] = b_hh[rg];
    }
    if (tid < 4) brol[tid] = (tid < dc) ? b_ro[d0 + tid] : 0.f;
    if (tid < 256) hloc[tid] = 0.f;
    __syncthreads();

    const float4* A4 = (const float4*)buf;
    const int u  = lane >> 4;
    const int bp = lane & 15;

    const bool have = (tid < dc * 64);
    const int dl = tid >> 6, b = tid & 63;
    const size_t gbase = (size_t)b * (SS * DD) + (d0 + dl);
    float xv_pf = 0.f, mv_pf = 0.f;
    if (have) { xv_pf = x[gbase]; mv_pf = mask[gbase]; }

    unsigned gen = 0;

    for (int t = 0; t < SS; ++t) {
        const int sbase = t * SROWS;        // this step's slot (row units)

        // ---- Phase R: readout-only mini-pass over h_t (virgin cached) ----
        {
            const int jb = wv * 32;
            const int gr0 = sbase + HOFF + jb;     // h rows (float4 rows)
            float4 cR = make_float4(0.f, 0.f, 0.f, 0.f);
            #pragma unroll 4
            for (int k = 0; k < 32; k += 4) {
                float4 a0 = A4[(gr0 + k + 0) * 16 + bp];
                float4 a1 = A4[(gr0 + k + 1) * 16 + bp];
                float4 a2 = A4[(gr0 + k + 2) * 16 + bp];
                float4 a3 = A4[(gr0 + k + 3) * 16 + bp];
                float4 wR = *(const float4*)&wrol[u * ROW + jb + k];
                cR.x += a0.x*wR.x + a1.x*wR.y + a2.x*wR.z + a3.x*wR.w;
                cR.y += a0.y*wR.x + a1.y*wR.y + a2.y*wR.z + a3.y*wR.w;
                cR.z += a0.z*wR.x + a1.z*wR.y + a2.z*wR.z + a3.z*wR.w;
                cR.w += a0.w*wR.x + a1.w*wR.y + a2.w*wR.z + a3.w*wR.w;
            }
            float4* RB4 = (float4*)redB;
            RB4[(wv * 4 + u) * 16 + bp] = cR;
        }
        __syncthreads();

        // ---- xh combine; publish x-hat + mask EARLY (no vmcnt yet) ----
        float xh = 0.f;
        if (have) {
            xh = brol[dl];
            #pragma unroll
            for (int g = 0; g < 8; ++g)
                xh += redB[(g * 4 + dl) * 64 + b];
            if (t < SS - 1) {
                float xi = (mv_pf > 0.5f) ? xv_pf : xh;
                ast4(&buf[(size_t)(sbase + d0 + dl) * 64 + b], xi);        // sc1
                ast4(&buf[(size_t)(sbase + 207 + d0 + dl) * 64 + b], mv_pf);
            }
        }
        if (t == SS - 1) {
            if (have) stage[(t * DD + d0 + dl) * 64 + b] = xh;
            break;
        }

        // ---- Phase G: gh gate pass (same 32 rows, L1-hot) -> slots 8-15 ----
        // The x-hat sc1 drain hides under this compute.
        run_range6(A4, wgl, red, u, bp, 416 + wv * 32, sbase + HOFF + wv * 32, 32, 8 + wv);

        // ---- arrive 1: drain + flag (ALL threads increment gen) ----
        ++gen;
        asm volatile("s_waitcnt vmcnt(0)" ::: "memory");
        __syncthreads();
        if (tid == 0)
            __hip_atomic_store(&flags[wg * 32], gen, __ATOMIC_RELAXED, AG);

        // deferred output store (out of the drain set)
        if (have) stage[(t * DD + d0 + dl) * 64 + b] = xh;

        // ---- wait 1 ----
        if (tid < 64) {
            unsigned* f = &flags[tid * 32];
            while (__hip_atomic_load(f, __ATOMIC_RELAXED, AG) < gen) {}
        }
        __syncthreads();

        // ---- gate xin GEMV: 8 waves x 52 rows (virgin cached reads) ----
        run_range6(A4, wgl, red, u, bp, wv * 52, sbase + wv * 52, 52, wv);
        __syncthreads();

        // ---- combine + gates + publish h_{t+1} into slot t+1 (sc1) ----
        if (tid < 256) {
            const int u2 = tid >> 6, b2 = tid & 63;
            float gir = bihl[0 + u2], giz = bihl[4 + u2], gin = bihl[8 + u2];
            float ghr = bhhl[0 + u2], ghz = bhhl[4 + u2], ghn = bhhl[8 + u2];
            #pragma unroll
            for (int s = 0; s < 8; ++s) {
                gir += red[(s * 12 + 0 + u2) * 64 + b2];
                giz += red[(s * 12 + 4 + u2) * 64 + b2];
                gin += red[(s * 12 + 8 + u2) * 64 + b2];
                ghr += red[((8 + s) * 12 + 0 + u2) * 64 + b2];
                ghz += red[((8 + s) * 12 + 4 + u2) * 64 + b2];
                ghn += red[((8 + s) * 12 + 8 + u2) * 64 + b2];
            }
            float r = 1.f / (1.f + __expf(-(gir + ghr)));
            float z = 1.f / (1.f + __expf(-(giz + ghz)));
            float n = tanhf(gin + r * ghn);
            float hn = (1.f - z) * n + z * hloc[u2 * 64 + b2];
            hloc[u2 * 64 + b2] = hn;
            ast4(&buf[(size_t)((t + 1) * SROWS + HOFF + wg * 4 + u2) * 64 + b2], hn);
        }

        // ---- arrive 2: h_{t+1} published (ALL threads increment gen) ----
        ++gen;
        asm volatile("s_waitcnt vmcnt(0)" ::: "memory");
        __syncthreads();
        if (tid == 0)
            __hip_atomic_store(&flags[wg * 32], gen, __ATOMIC_RELAXED, AG);

        // ---- overlap: next x/mask prefetch ----
        if (have && t + 1 < SS - 1) {
            xv_pf = x[gbase + (size_t)(t + 1) * DD];
            mv_pf = mask[gbase + (size_t)(t + 1) * DD];
        }

        // ---- wait 2 ----
        if (tid < 64) {
            unsigned* f = &flags[tid * 32];
            while (__hip_atomic_load(f, __ATOMIC_RELAXED, AG) < gen) {}
        }
        __syncthreads();
    }
}

// epilogue: stage[t][d][b] -> out[b][t][d]
__global__ __launch_bounds__(256) void out_transpose(
    const float* __restrict__ stage, float* __restrict__ out)
{
    __shared__ float lds[DD * 65];
    const int t = blockIdx.x;
    const float* st = stage + (size_t)t * DD * 64;
    for (int i = threadIdx.x; i < DD * 64; i += 256) {
        int d = i >> 6, b = i & 63;
        lds[d * 65 + b] = st[i];
    }
    __syncthreads();
    for (int i = threadIdx.x; i < DD * 64; i += 256) {
        int b = i / DD, d = i - b * DD;
        out[(size_t)b * (SS * DD) + (size_t)t * DD + d] = lds[d * 65 + b];
    }
}

// ================= v3 middle fallback (round-3 proven, 8.1 ms) =================
__device__ __forceinline__ void v3_gbar(unsigned* flags, int wg, unsigned g) {
    __syncthreads();
    if (threadIdx.x < 64) {
        if (threadIdx.x == 0) {
            __builtin_amdgcn_fence(__ATOMIC_RELEASE, "agent");
            __hip_atomic_store(&flags[wg * 32], g, __ATOMIC_RELAXED, AG);
        }
        unsigned* f = &flags[threadIdx.x * 32];
        while (__hip_atomic_load(f, __ATOMIC_RELAXED, AG) < g) { }
        __builtin_amdgcn_fence(__ATOMIC_ACQUIRE, "agent");
    }
    __syncthreads();
}

__global__ __launch_bounds__(256) void v3_init(float* __restrict__ ws) {
    int i = blockIdx.x * blockDim.x + threadIdx.x;
    const int nz = (672 - 414) * 64;
    for (int idx = i; idx < nz; idx += gridDim.x * blockDim.x)
        ws[414 * 64 + idx] = 0.f;
    for (int idx = i; idx < V3_FLAGS; idx += gridDim.x * blockDim.x)
        ((unsigned*)(ws + V3_ACT))[idx] = 0u;
}

template<bool STAGE>
__global__ __launch_bounds__(256) void v3_persist(
    const float* __restrict__ x, const float* __restrict__ mask,
    const float* __restrict__ W_ih, const float* __restrict__ W_hh,
    const float* __restrict__ b_ih, const float* __restrict__ b_hh,
    const float* __restrict__ W_ro, const float* __restrict__ b_ro,
    float* __restrict__ ws, float* __restrict__ out)
{
    const int wg = blockIdx.x;
    const int tid = threadIdx.x;
    const int lane = tid & 63;
    const int wv = tid >> 6;

    float* actg = ws;
    unsigned* flags = (unsigned*)(ws + V3_ACT);
    float* stage = ws + V3_ACT + V3_FLAGS;

    __shared__ float wgl[12 * LDW];
    __shared__ float wrol[4 * 256];
    __shared__ float red[5 * 12 * 64];
    __shared__ float redB[16 * 64];
    __shared__ float hloc[4 * 64];
    __shared__ float bihl[12], bhhl[12], brol[4];

    const int d0 = (207 * wg) / NWG;
    const int d1 = (207 * (wg + 1)) / NWG;
    const int dc = d1 - d0;

    for (int i = tid; i < 12 * LDW; i += 256) {
        int r = i / LDW, c = i - r * LDW;
        int rg = (r >> 2) * 256 + wg * 4 + (r & 3);
        float v = 0.f;
        if (c < 414) v = W_ih[rg * 414 + c];
        else if (c >= 416 && c < 672) v = W_hh[rg * 256 + (c - 416)];
        wgl[i] = v;
    }
    for (int i = tid; i < 4 * 256; i += 256) {
        int dl_ = i >> 8, j = i & 255;
        wrol[i] = (dl_ < dc) ? W_ro[(d0 + dl_) * 256 + j] : 0.f;
    }
    if (tid < 12) {
        int rg = (tid >> 2) * 256 + wg * 4 + (tid & 3);
        bihl[tid] = b_ih[rg];
        bhhl[tid] = b_hh[rg];
    }
    if (tid < 4) brol[tid] = (tid < dc) ? b_ro[d0 + tid] : 0.f;
    hloc[tid] = 0.f;
    __syncthreads();

    const float4* A4 = (const float4*)actg;
    const int u = lane >> 4;
    const int bp = lane & 15;

    const bool have = (tid < dc * 64);
    const int dl = tid >> 6, b = tid & 63;
    const size_t gbase = (size_t)b * (SS * DD) + (d0 + dl);
    float xv_pf = 0.f, mv_pf = 0.f;
    if (have) { xv_pf = x[gbase]; mv_pf = mask[gbase]; }

    unsigned gen = 0;

    for (int t = 0; t < SS; ++t) {
        const int par = t & 1;
        const int hrow0 = V3_HBASE + par * 256;

        {
            const float* hrow = actg + hrow0 * 64;
            const int jb = wv * 64;
            float acc0 = 0.f, acc1 = 0.f, acc2 = 0.f, acc3 = 0.f;
            #pragma unroll 4
            for (int j = 0; j < 64; j += 4) {
                float a0 = hrow[(jb + j + 0) * 64 + lane];
                float a1 = hrow[(jb + j + 1) * 64 + lane];
                float a2 = hrow[(jb + j + 2) * 64 + lane];
                float a3 = hrow[(jb + j + 3) * 64 + lane];
                float4 w0 = *(const float4*)&wrol[0 * 256 + jb + j];
                float4 w1 = *(const float4*)&wrol[1 * 256 + jb + j];
                float4 w2 = *(const float4*)&wrol[2 * 256 + jb + j];
                float4 w3 = *(const float4*)&wrol[3 * 256 + jb + j];
                acc0 += a0*w0.x + a1*w0.y + a2*w0.z + a3*w0.w;
                acc1 += a0*w1.x + a1*w1.y + a2*w1.z + a3*w1.w;
                acc2 += a0*w2.x + a1*w2.y + a2*w2.z + a3*w2.w;
                acc3 += a0*w3.x + a1*w3.y + a2*w3.z + a3*w3.w;
            }
            redB[(wv * 4 + 0) * 64 + lane] = acc0;
            redB[(wv * 4 + 1) * 64 + lane] = acc1;
            redB[(wv * 4 + 2) * 64 + lane] = acc2;
            redB[(wv * 4 + 3) * 64 + lane] = acc3;
        }
        __syncthreads();
        if (have) {
            float xh = redB[(0 * 4 + dl) * 64 + b] + redB[(1 * 4 + dl) * 64 + b]
                     + redB[(2 * 4 + dl) * 64 + b] + redB[(3 * 4 + dl) * 64 + b]
                     + brol[dl];
            if (STAGE) stage[(t * DD + d0 + dl) * 64 + b] = xh;
            else       out[gbase + (size_t)t * DD] = xh;
            if (t < SS - 1) {
                float xi = (mv_pf > 0.5f) ? xv_pf : xh;
                actg[(d0 + dl) * 64 + b] = xi;
                actg[(207 + d0 + dl) * 64 + b] = mv_pf;
            }
        }
        if (t == SS - 1) break;

        if (have && t + 1 < SS - 1) {
            xv_pf = x[gbase + (size_t)(t + 1) * DD];
            mv_pf = mask[gbase + (size_t)(t + 1) * DD];
        }

        v3_gbar(flags, wg, ++gen);

        if (wv == 0)      run_range6(A4, wgl, red, u, bp, 0,   0,          168, 0);
        else if (wv == 1) run_range6(A4, wgl, red, u, bp, 168, 168,        168, 1);
        else if (wv == 2) {
            run_range6(A4, wgl, red, u, bp, 336, 336,        80,  2);
            run_range6(A4, wgl, red, u, bp, 416, hrow0,      96,  3);
        } else            run_range6(A4, wgl, red, u, bp, 512, hrow0 + 96, 160, 4);
        __syncthreads();
        {
            const int u2 = tid >> 6, b2 = tid & 63;
            float gir = red[(0*12 + 0 + u2)*64 + b2] + red[(1*12 + 0 + u2)*64 + b2]
                      + red[(2*12 + 0 + u2)*64 + b2] + bihl[0 + u2];
            float giz = red[(0*12 + 4 + u2)*64 + b2] + red[(1*12 + 4 + u2)*64 + b2]
                      + red[(2*12 + 4 + u2)*64 + b2] + bihl[4 + u2];
            float gin = red[(0*12 + 8 + u2)*64 + b2] + red[(1*12 + 8 + u2)*64 + b2]
                      + red[(2*12 + 8 + u2)*64 + b2] + bihl[8 + u2];
            float ghr = red[(3*12 + 0 + u2)*64 + b2] + red[(4*12 + 0 + u2)*64 + b2] + bhhl[0 + u2];
            float ghz = red[(3*12 + 4 + u2)*64 + b2] + red[(4*12 + 4 + u2)*64 + b2] + bhhl[4 + u2];
            float ghn = red[(3*12 + 8 + u2)*64 + b2] + red[(4*12 + 8 + u2)*64 + b2] + bhhl[8 + u2];
            float r = 1.f / (1.f + __expf(-(gir + ghr)));
            float z = 1.f / (1.f + __expf(-(giz + ghz)));
            float n = tanhf(gin + r * ghn);
            float hn = (1.f - z) * n + z * hloc[u2 * 64 + b2];
            hloc[u2 * 64 + b2] = hn;
            actg[(V3_HBASE + (par ^ 1) * 256 + wg * 4 + u2) * 64 + b2] = hn;
        }
        v3_gbar(flags, wg, ++gen);
    }
}

// ---- minimal fallback (one WG per batch) ----
__global__ __launch_bounds__(768) void rnn_fallback(
    const float* __restrict__ x, const float* __restrict__ mask,
    const float* __restrict__ W_ih, const float* __restrict__ W_hh,
    const float* __restrict__ b_ih, const float* __restrict__ b_hh,
    const float* __restrict__ W_ro, const float* __restrict__ b_ro,
    float* __restrict__ out)
{
    const int b = blockIdx.x, tid = threadIdx.x;
    __shared__ float h[HH];
    __shared__ float hnew[HH];
    __shared__ float xin[414 + 2];
    __shared__ float gi[768];
    __shared__ float gh[768];
    __shared__ float xhat[DD];
    const float bih = b_ih[tid], bhh = b_hh[tid];
    const float bro = (tid < DD) ? b_ro[tid] : 0.f;
    if (tid < HH) h[tid] = 0.f;
    if (tid < DD) xhat[tid] = bro;
    __syncthreads();
    const float* xb = x + (size_t)b * SS * DD;
    const float* mb = mask + (size_t)b * SS * DD;
    float* ob = out + (size_t)b * SS * DD;
    for (int t = 0; t < SS; ++t) {
        if (tid < DD) ob[t * DD + tid] = xhat[tid];
        if (t == SS - 1) break;
        if (tid < DD) {
            float m = mb[t * DD + tid], xv = xb[t * DD + tid];
            xin[tid] = (m > 0.5f) ? xv : xhat[tid];
            xin[DD + tid] = m;
        }
        __syncthreads();
        float accI = bih, accH = bhh;
        const float* wi = W_ih + (size_t)tid * 414;
        for (int k = 0; k < 414; ++k) accI += wi[k] * xin[k];
        const float* wh = W_hh + (size_t)tid * HH;
        for (int k = 0; k < HH; ++k) accH += wh[k] * h[k];
        gi[tid] = accI; gh[tid] = accH;
        __syncthreads();
        if (tid < HH) {
            float r = 1.f / (1.f + __expf(-(gi[tid] + gh[tid])));
            float z = 1.f / (1.f + __expf(-(gi[HH + tid] + gh[HH + tid])));
            float n = tanhf(gi[2 * HH + tid] + r * gh[2 * HH + tid]);
            hnew[tid] = (1.f - z) * n + z * h[tid];
        }
        __syncthreads();
        if (tid < DD) {
            float acc = bro;
            const float* wr = W_ro + (size_t)tid * HH;
            for (int k = 0; k < HH; ++k) acc += wr[k] * hnew[k];
            xhat[tid] = acc;
        }
        if (tid < HH) h[tid] = hnew[tid];
        __syncthreads();
    }
}

extern "C" void kernel_launch(void* const* d_in, const int* in_sizes, int n_in,
                              void* d_out, int out_size, void* d_ws, size_t ws_size,
                              hipStream_t stream) {
    const float* x    = (const float*)d_in[0];
    const float* mask = (const float*)d_in[1];
    const float* W_ih = (const float*)d_in[2];
    const float* W_hh = (const float*)d_in[3];
    const float* b_ih = (const float*)d_in[4];
    const float* b_hh = (const float*)d_in[5];
    const float* W_ro = (const float*)d_in[6];
    const float* b_ro = (const float*)d_in[7];
    float* out = (float*)d_out;
    float* ws  = (float*)d_ws;

    if (ws_size >= WS_NEED6) {
        hipLaunchKernelGGL(rnn_init6, dim3(64), dim3(256), 0, stream, ws);
        hipLaunchKernelGGL(rnn_persist17, dim3(NWG), dim3(512), 0, stream,
                           x, mask, W_ih, W_hh, b_ih, b_hh, W_ro, b_ro, ws, out);
        hipLaunchKernelGGL(out_transpose, dim3(SS), dim3(256), 0, stream,
                           ws + BUF_FLOATS + FLAG_U32, out);
    } else if (ws_size >= V3_WS_FULL) {
        hipLaunchKernelGGL(v3_init, dim3(32), dim3(256), 0, stream, ws);
        hipLaunchKernelGGL((v3_persist<true>), dim3(NWG), dim3(256), 0, stream,
                           x, mask, W_ih, W_hh, b_ih, b_hh, W_ro, b_ro, ws, out);
        hipLaunchKernelGGL(out_transpose, dim3(SS), dim3(256), 0, stream,
                           ws + V3_ACT + V3_FLAGS, out);
    } else if (ws_size >= V3_WS_SMALL) {
        hipLaunchKernelGGL(v3_init, dim3(32), dim3(256), 0, stream, ws);
        hipLaunchKernelGGL((v3_persist<false>), dim3(NWG), dim3(256), 0, stream,
                           x, mask, W_ih, W_hh, b_ih, b_hh, W_ro, b_ro, ws, out);
    } else {
        hipLaunchKernelGGL(rnn_fallback, dim3(BB), dim3(768), 0, stream,
                           x, mask, W_ih, W_hh, b_ih, b_hh, W_ro, b_ro, out);
    }
}

// Round 13
// 5925.871 us; speedup vs baseline: 1.0199x; 1.0199x over previous
//
#include <hip/hip_runtime.h>
#include <math.h>

#define BB 64
#define SS 512
#define DD 207
#define HH 256
#define NWG 64
#define LDW 676   // wgl row stride (%32==4 -> staggered banks)
#define ROW 260   // wrol row stride
#define AG __HIP_MEMORY_SCOPE_AGENT

// ================= v18: v13 + k-split xin GEMV (52 -> 13 loads/thread) ======
// 64 WGs x 512 threads, v13's protocol/layout/flags and fused PhaseB+gh pass
// UNCHANGED. Change: the critical post-wait1 xin GEMV no longer has all 4
// u-groups of a wave issue the same 52 A-loads (u only selected weights).
// Instead each u-group covers a DISTINCT 13-row k-range and accumulates ALL
// 12 gate rows (12 float4 accumulators), reading weights from a transposed
// LDS copy wgT[416][16] (built once at init; per-u row broadcast, 2-way bank
// alias = free). A 2-stage __shfl_xor butterfly (^16, ^32) folds the 4
// u-partials in-register; each u-group stores its 3 rows into the SAME red
// layout (slot wv) -> combine unchanged. Same FMA & LDS-read counts; global
// loads/thread 52 -> 13 => exposed-latency rounds ~7 -> ~2 on the serial
// chain. LDS ~122 KB (still 1 WG/CU; 64 WGs on 64 CUs).
#define SROWS 672
#define HOFF  416
#define SLOT  (SROWS * 64)
#define BUF_FLOATS ((size_t)SS * SLOT)
#define FLAG_U32 (64 * 32)
#define STAGE_FLOATS ((size_t)SS * DD * 64)
#define WS_NEED6 ((BUF_FLOATS + FLAG_U32 + STAGE_FLOATS) * sizeof(float))

// ---- v3 fallback layout (round-3 proven path) ----
#define V3_AROWS 928
#define V3_HBASE 416
#define V3_ACT (V3_AROWS * 64)
#define V3_FLAGS (64 * 32)
#define V3_WS_SMALL ((size_t)(V3_ACT + V3_FLAGS) * sizeof(float))
#define V3_WS_FULL  ((size_t)(V3_ACT + V3_FLAGS + STAGE_FLOATS) * sizeof(float))

__device__ __forceinline__ void ast4(float* p, float v) {
    union { float f; unsigned u; } c; c.f = v;
    __hip_atomic_store((unsigned*)p, c.u, __ATOMIC_RELAXED, AG);
}

// 12-row (3 gates x unit u) GEMV partial, NORMAL float4 loads (round-3 shape).
// gr0 = global float4-row base (t*672 + local row), wc0 = weight col base.
__device__ __forceinline__ void run_range6(
    const float4* __restrict__ A4, const float* __restrict__ wgl,
    float* __restrict__ red, int u, int bp, int wc0, int gr0, int len, int slot)
{
    float4 c0 = make_float4(0.f, 0.f, 0.f, 0.f);
    float4 c1 = c0, c2 = c0;
    #pragma unroll 4
    for (int k = 0; k < len; k += 4) {
        float4 a0 = A4[(gr0 + k + 0) * 16 + bp];
        float4 a1 = A4[(gr0 + k + 1) * 16 + bp];
        float4 a2 = A4[(gr0 + k + 2) * 16 + bp];
        float4 a3 = A4[(gr0 + k + 3) * 16 + bp];
        float4 w0 = *(const float4*)&wgl[(0 + u) * LDW + wc0 + k];
        float4 w1 = *(const float4*)&wgl[(4 + u) * LDW + wc0 + k];
        float4 w2 = *(const float4*)&wgl[(8 + u) * LDW + wc0 + k];
        c0.x += a0.x*w0.x + a1.x*w0.y + a2.x*w0.z + a3.x*w0.w;
        c0.y += a0.y*w0.x + a1.y*w0.y + a2.y*w0.z + a3.y*w0.w;
        c0.z += a0.z*w0.x + a1.z*w0.y + a2.z*w0.z + a3.z*w0.w;
        c0.w += a0.w*w0.x + a1.w*w0.y + a2.w*w0.z + a3.w*w0.w;
        c1.x += a0.x*w1.x + a1.x*w1.y + a2.x*w1.z + a3.x*w1.w;
        c1.y += a0.y*w1.x + a1.y*w1.y + a2.y*w1.z + a3.y*w1.w;
        c1.z += a0.z*w1.x + a1.z*w1.y + a2.z*w1.z + a3.z*w1.w;
        c1.w += a0.w*w1.x + a1.w*w1.y + a2.w*w1.z + a3.w*w1.w;
        c2.x += a0.x*w2.x + a1.x*w2.y + a2.x*w2.z + a3.x*w2.w;
        c2.y += a0.y*w2.x + a1.y*w2.y + a2.y*w2.z + a3.y*w2.w;
        c2.z += a0.z*w2.x + a1.z*w2.y + a2.z*w2.z + a3.z*w2.w;
        c2.w += a0.w*w2.x + a1.w*w2.y + a2.w*w2.z + a3.w*w2.w;
    }
    float4* R4 = (float4*)red;
    R4[(slot * 12 + 0 + u) * 16 + bp] = c0;
    R4[(slot * 12 + 4 + u) * 16 + bp] = c1;
    R4[(slot * 12 + 8 + u) * 16 + bp] = c2;
}

__global__ __launch_bounds__(256) void rnn_init6(float* __restrict__ ws) {
    int i = blockIdx.x * blockDim.x + threadIdx.x;
    // zero slot-0 h rows (h_0 = 0)
    for (int idx = i; idx < HH * 64; idx += gridDim.x * blockDim.x)
        ws[HOFF * 64 + idx] = 0.f;
    unsigned* fl = (unsigned*)(ws + BUF_FLOATS);
    for (int idx = i; idx < FLAG_U32; idx += gridDim.x * blockDim.x)
        fl[idx] = 0u;
}

#define BFLY(c) \
    c.x += __shfl_xor(c.x, 16); c.y += __shfl_xor(c.y, 16); \
    c.z += __shfl_xor(c.z, 16); c.w += __shfl_xor(c.w, 16); \
    c.x += __shfl_xor(c.x, 32); c.y += __shfl_xor(c.y, 32); \
    c.z += __shfl_xor(c.z, 32); c.w += __shfl_xor(c.w, 32);

__global__ __launch_bounds__(512) void rnn_persist18(
    const float* __restrict__ x, const float* __restrict__ mask,
    const float* __restrict__ W_ih, const float* __restrict__ W_hh,
    const float* __restrict__ b_ih, const float* __restrict__ b_hh,
    const float* __restrict__ W_ro, const float* __restrict__ b_ro,
    float* __restrict__ ws, float* __restrict__ out)
{
    const int wg = blockIdx.x;
    const int tid = threadIdx.x;
    const int lane = tid & 63;
    const int wv = tid >> 6;          // 0..7

    float* buf = ws;
    unsigned* flags = (unsigned*)(ws + BUF_FLOATS);
    float* stage = ws + BUF_FLOATS + FLAG_U32;

    __shared__ float wgl[12 * LDW];      // 12 gate rows x 676 (cols 414/415 = 0)
    __shared__ float wgT[416 * 16];      // transposed W_ih cols: [row][gate 0-11, pad]
    __shared__ float wrol[4 * ROW];      // up to 4 readout rows
    __shared__ float red[16 * 12 * 64];  // slots 0-7 xin partials, 8-15 gh
    __shared__ float redB[32 * 64];      // readout partials (8 waves x 4 rows)
    __shared__ float hloc[4 * 64];       // own hidden units
    __shared__ float bihl[12], bhhl[12], brol[4];

    const int d0 = (207 * wg) / NWG;
    const int d1 = (207 * (wg + 1)) / NWG;
    const int dc = d1 - d0;

    for (int i = tid; i < 12 * LDW; i += 512) {
        int r = i / LDW, c = i - r * LDW;
        int rg = (r >> 2) * 256 + wg * 4 + (r & 3);
        float v = 0.f;
        if (c < 414) v = W_ih[rg * 414 + c];
        else if (c >= 416 && c < 672) v = W_hh[rg * 256 + (c - 416)];
        wgl[i] = v;
    }
    // transposed copy for the k-split xin pass: wgT[r][j] = W_ih[rg(j)][r]
    for (int i = tid; i < 416 * 16; i += 512) {
        int r = i >> 4, j = i & 15;
        float v = 0.f;
        if (j < 12 && r < 414) {
            int rg = (j >> 2) * 256 + wg * 4 + (j & 3);
            v = W_ih[rg * 414 + r];
        }
        wgT[i] = v;
    }
    for (int i = tid; i < 4 * 256; i += 512) {
        int dl_ = i >> 8, j = i & 255;
        wrol[dl_ * ROW + j] = (dl_ < dc) ? W_ro[(d0 + dl_) * 256 + j] : 0.f;
    }
    if (tid < 12) {
        int rg = (tid >> 2) * 256 + wg * 4 + (tid & 3);
        bihl[tid] = b_ih[rg];
        bhhl[tid] = b_hh[rg];
    }
    if (tid < 4) brol[tid] = (tid < dc) ? b_ro[d0 + tid] : 0.f;
    if (tid < 256) hloc[tid] = 0.f;
    __syncthreads();

    const float4* A4 = (const float4*)buf;
    const int u  = lane >> 4;
    const int bp = lane & 15;

    const bool have = (tid < dc * 64);
    const int dl = tid >> 6, b = tid & 63;
    const size_t gbase = (size_t)b * (SS * DD) + (d0 + dl);
    float xv_pf = 0.f, mv_pf = 0.f;
    if (have) { xv_pf = x[gbase]; mv_pf = mask[gbase]; }

    unsigned gen = 0;

    for (int t = 0; t < SS; ++t) {
        const int sbase = t * SROWS;        // this step's slot (row units)

        // ---- Fused Phase B + gh: ONE pass over h_t (float4, virgin reads) ----
        {
            const int jb = wv * 32;
            const int gr0 = sbase + HOFF + jb;     // h rows (float4 rows)
            const int wc0 = 416 + jb;              // gate weight cols
            float4 c0 = make_float4(0.f, 0.f, 0.f, 0.f);
            float4 c1 = c0, c2 = c0, cR = c0;
            #pragma unroll 4
            for (int k = 0; k < 32; k += 4) {
                float4 a0 = A4[(gr0 + k + 0) * 16 + bp];
                float4 a1 = A4[(gr0 + k + 1) * 16 + bp];
                float4 a2 = A4[(gr0 + k + 2) * 16 + bp];
                float4 a3 = A4[(gr0 + k + 3) * 16 + bp];
                float4 w0 = *(const float4*)&wgl[(0 + u) * LDW + wc0 + k];
                float4 w1 = *(const float4*)&wgl[(4 + u) * LDW + wc0 + k];
                float4 w2 = *(const float4*)&wgl[(8 + u) * LDW + wc0 + k];
                float4 wR = *(const float4*)&wrol[u * ROW + jb + k];
                c0.x += a0.x*w0.x + a1.x*w0.y + a2.x*w0.z + a3.x*w0.w;
                c0.y += a0.y*w0.x + a1.y*w0.y + a2.y*w0.z + a3.y*w0.w;
                c0.z += a0.z*w0.x + a1.z*w0.y + a2.z*w0.z + a3.z*w0.w;
                c0.w += a0.w*w0.x + a1.w*w0.y + a2.w*w0.z + a3.w*w0.w;
                c1.x += a0.x*w1.x + a1.x*w1.y + a2.x*w1.z + a3.x*w1.w;
                c1.y += a0.y*w1.x + a1.y*w1.y + a2.y*w1.z + a3.y*w1.w;
                c1.z += a0.z*w1.x + a1.z*w1.y + a2.z*w1.z + a3.z*w1.w;
                c1.w += a0.w*w1.x + a1.w*w1.y + a2.w*w1.z + a3.w*w1.w;
                c2.x += a0.x*w2.x + a1.x*w2.y + a2.x*w2.z + a3.x*w2.w;
                c2.y += a0.y*w2.x + a1.y*w2.y + a2.y*w2.z + a3.y*w2.w;
                c2.z += a0.z*w2.x + a1.z*w2.y + a2.z*w2.z + a3.z*w2.w;
                c2.w += a0.w*w2.x + a1.w*w2.y + a2.w*w2.z + a3.w*w2.w;
                cR.x += a0.x*wR.x + a1.x*wR.y + a2.x*wR.z + a3.x*wR.w;
                cR.y += a0.y*wR.x + a1.y*wR.y + a2.y*wR.z + a3.y*wR.w;
                cR.z += a0.z*wR.x + a1.z*wR.y + a2.z*wR.z + a3.z*wR.w;
                cR.w += a0.w*wR.x + a1.w*wR.y + a2.w*wR.z + a3.w*wR.w;
            }
            float4* R4 = (float4*)red;
            R4[((8 + wv) * 12 + 0 + u) * 16 + bp] = c0;
            R4[((8 + wv) * 12 + 4 + u) * 16 + bp] = c1;
            R4[((8 + wv) * 12 + 8 + u) * 16 + bp] = c2;
            float4* RB4 = (float4*)redB;
            RB4[(wv * 4 + u) * 16 + bp] = cR;
        }
        __syncthreads();

        float xh = 0.f;
        if (have) {
            xh = brol[dl];
            #pragma unroll
            for (int g = 0; g < 8; ++g)
                xh += redB[(g * 4 + dl) * 64 + b];
            if (t < SS - 1) {
                float xi = (mv_pf > 0.5f) ? xv_pf : xh;
                ast4(&buf[(size_t)(sbase + d0 + dl) * 64 + b], xi);        // sc1
                ast4(&buf[(size_t)(sbase + 207 + d0 + dl) * 64 + b], mv_pf);
            }
        }
        if (t == SS - 1) {
            if (have) stage[(t * DD + d0 + dl) * 64 + b] = xh;
            break;
        }

        // ---- arrive 1: xin_t published (drain = 2 ast4 only) ----
        ++gen;
        asm volatile("s_waitcnt vmcnt(0)" ::: "memory");
        __syncthreads();
        if (tid == 0)
            __hip_atomic_store(&flags[wg * 32], gen, __ATOMIC_RELAXED, AG);

        // deferred output store (out of the drain set)
        if (have) stage[(t * DD + d0 + dl) * 64 + b] = xh;

        // ---- wait 1 ----
        if (tid < 64) {
            unsigned* f = &flags[tid * 32];
            while (__hip_atomic_load(f, __ATOMIC_RELAXED, AG) < gen) {}
        }
        __syncthreads();

        // ---- xin GEMV, k-split: u-group covers 13 distinct rows, ALL 12
        //      gate rows accumulated; butterfly folds u-partials ----
        {
            const int base = wv * 52 + u * 13;
            const int gr = sbase + base;
            float4 c0 = make_float4(0.f,0.f,0.f,0.f);
            float4 c1=c0,c2=c0,c3=c0,c4=c0,c5=c0,c6=c0,c7=c0,c8=c0,c9=c0,c10=c0,c11=c0;
            #pragma unroll
            for (int k = 0; k < 13; ++k) {
                float4 a = A4[(gr + k) * 16 + bp];
                const float* wt = &wgT[(base + k) * 16];
                float4 wA = *(const float4*)(wt);
                float4 wB = *(const float4*)(wt + 4);
                float4 wC = *(const float4*)(wt + 8);
                c0.x += a.x*wA.x; c0.y += a.y*wA.x; c0.z += a.z*wA.x; c0.w += a.w*wA.x;
                c1.x += a.x*wA.y; c1.y += a.y*wA.y; c1.z += a.z*wA.y; c1.w += a.w*wA.y;
                c2.x += a.x*wA.z; c2.y += a.y*wA.z; c2.z += a.z*wA.z; c2.w += a.w*wA.z;
                c3.x += a.x*wA.w; c3.y += a.y*wA.w; c3.z += a.z*wA.w; c3.w += a.w*wA.w;
                c4.x += a.x*wB.x; c4.y += a.y*wB.x; c4.z += a.z*wB.x; c4.w += a.w*wB.x;
                c5.x += a.x*wB.y; c5.y += a.y*wB.y; c5.z += a.z*wB.y; c5.w += a.w*wB.y;
                c6.x += a.x*wB.z; c6.y += a.y*wB.z; c6.z += a.z*wB.z; c6.w += a.w*wB.z;
                c7.x += a.x*wB.w; c7.y += a.y*wB.w; c7.z += a.z*wB.w; c7.w += a.w*wB.w;
                c8.x += a.x*wC.x; c8.y += a.y*wC.x; c8.z += a.z*wC.x; c8.w += a.w*wC.x;
                c9.x += a.x*wC.y; c9.y += a.y*wC.y; c9.z += a.z*wC.y; c9.w += a.w*wC.y;
                c10.x += a.x*wC.z; c10.y += a.y*wC.z; c10.z += a.z*wC.z; c10.w += a.w*wC.z;
                c11.x += a.x*wC.w; c11.y += a.y*wC.w; c11.z += a.z*wC.w; c11.w += a.w*wC.w;
            }
            BFLY(c0); BFLY(c1); BFLY(c2); BFLY(c3);
            BFLY(c4); BFLY(c5); BFLY(c6); BFLY(c7);
            BFLY(c8); BFLY(c9); BFLY(c10); BFLY(c11);
            float4* R4 = (float4*)red;
            if (u == 0) {
                R4[(wv * 12 + 0) * 16 + bp] = c0;
                R4[(wv * 12 + 4) * 16 + bp] = c4;
                R4[(wv * 12 + 8) * 16 + bp] = c8;
            } else if (u == 1) {
                R4[(wv * 12 + 1) * 16 + bp] = c1;
                R4[(wv * 12 + 5) * 16 + bp] = c5;
                R4[(wv * 12 + 9) * 16 + bp] = c9;
            } else if (u == 2) {
                R4[(wv * 12 + 2) * 16 + bp] = c2;
                R4[(wv * 12 + 6) * 16 + bp] = c6;
                R4[(wv * 12 + 10) * 16 + bp] = c10;
            } else {
                R4[(wv * 12 + 3) * 16 + bp] = c3;
                R4[(wv * 12 + 7) * 16 + bp] = c7;
                R4[(wv * 12 + 11) * 16 + bp] = c11;
            }
        }
        __syncthreads();

        // ---- combine + gates + publish h_{t+1} into slot t+1 (sc1) ----
        if (tid < 256) {
            const int u2 = tid >> 6, b2 = tid & 63;
            float gir = bihl[0 + u2], giz = bihl[4 + u2], gin = bihl[8 + u2];
            float ghr = bhhl[0 + u2], ghz = bhhl[4 + u2], ghn = bhhl[8 + u2];
            #pragma unroll
            for (int s = 0; s < 8; ++s) {
                gir += red[(s * 12 + 0 + u2) * 64 + b2];
                giz += red[(s * 12 + 4 + u2) * 64 + b2];
                gin += red[(s * 12 + 8 + u2) * 64 + b2];
                ghr += red[((8 + s) * 12 + 0 + u2) * 64 + b2];
                ghz += red[((8 + s) * 12 + 4 + u2) * 64 + b2];
                ghn += red[((8 + s) * 12 + 8 + u2) * 64 + b2];
            }
            float r = 1.f / (1.f + __expf(-(gir + ghr)));
            float z = 1.f / (1.f + __expf(-(giz + ghz)));
            float n = tanhf(gin + r * ghn);
            float hn = (1.f - z) * n + z * hloc[u2 * 64 + b2];
            hloc[u2 * 64 + b2] = hn;
            ast4(&buf[(size_t)((t + 1) * SROWS + HOFF + wg * 4 + u2) * 64 + b2], hn);
        }

        // ---- arrive 2: h_{t+1} published ----
        ++gen;
        asm volatile("s_waitcnt vmcnt(0)" ::: "memory");
        __syncthreads();
        if (tid == 0)
            __hip_atomic_store(&flags[wg * 32], gen, __ATOMIC_RELAXED, AG);

        // ---- overlap: next x/mask prefetch ----
        if (have && t + 1 < SS - 1) {
            xv_pf = x[gbase + (size_t)(t + 1) * DD];
            mv_pf = mask[gbase + (size_t)(t + 1) * DD];
        }

        // ---- wait 2 ----
        if (tid < 64) {
            unsigned* f = &flags[tid * 32];
            while (__hip_atomic_load(f, __ATOMIC_RELAXED, AG) < gen) {}
        }
        __syncthreads();
    }
}

// epilogue: stage[t][d][b] -> out[b][t][d]
__global__ __launch_bounds__(256) void out_transpose(
    const float* __restrict__ stage, float* __restrict__ out)
{
    __shared__ float lds[DD * 65];
    const int t = blockIdx.x;
    const float* st = stage + (size_t)t * DD * 64;
    for (int i = threadIdx.x; i < DD * 64; i += 256) {
        int d = i >> 6, b = i & 63;
        lds[d * 65 + b] = st[i];
    }
    __syncthreads();
    for (int i = threadIdx.x; i < DD * 64; i += 256) {
        int b = i / DD, d = i - b * DD;
        out[(size_t)b * (SS * DD) + (size_t)t * DD + d] = lds[d * 65 + b];
    }
}

// ================= v3 middle fallback (round-3 proven, 8.1 ms) =================
__device__ __forceinline__ void v3_gbar(unsigned* flags, int wg, unsigned g) {
    __syncthreads();
    if (threadIdx.x < 64) {
        if (threadIdx.x == 0) {
            __builtin_amdgcn_fence(__ATOMIC_RELEASE, "agent");
            __hip_atomic_store(&flags[wg * 32], g, __ATOMIC_RELAXED, AG);
        }
        unsigned* f = &flags[threadIdx.x * 32];
        while (__hip_atomic_load(f, __ATOMIC_RELAXED, AG) < g) { }
        __builtin_amdgcn_fence(__ATOMIC_ACQUIRE, "agent");
    }
    __syncthreads();
}

__global__ __launch_bounds__(256) void v3_init(float* __restrict__ ws) {
    int i = blockIdx.x * blockDim.x + threadIdx.x;
    const int nz = (672 - 414) * 64;
    for (int idx = i; idx < nz; idx += gridDim.x * blockDim.x)
        ws[414 * 64 + idx] = 0.f;
    for (int idx = i; idx < V3_FLAGS; idx += gridDim.x * blockDim.x)
        ((unsigned*)(ws + V3_ACT))[idx] = 0u;
}

template<bool STAGE>
__global__ __launch_bounds__(256) void v3_persist(
    const float* __restrict__ x, const float* __restrict__ mask,
    const float* __restrict__ W_ih, const float* __restrict__ W_hh,
    const float* __restrict__ b_ih, const float* __restrict__ b_hh,
    const float* __restrict__ W_ro, const float* __restrict__ b_ro,
    float* __restrict__ ws, float* __restrict__ out)
{
    const int wg = blockIdx.x;
    const int tid = threadIdx.x;
    const int lane = tid & 63;
    const int wv = tid >> 6;

    float* actg = ws;
    unsigned* flags = (unsigned*)(ws + V3_ACT);
    float* stage = ws + V3_ACT + V3_FLAGS;

    __shared__ float wgl[12 * LDW];
    __shared__ float wrol[4 * 256];
    __shared__ float red[5 * 12 * 64];
    __shared__ float redB[16 * 64];
    __shared__ float hloc[4 * 64];
    __shared__ float bihl[12], bhhl[12], brol[4];

    const int d0 = (207 * wg) / NWG;
    const int d1 = (207 * (wg + 1)) / NWG;
    const int dc = d1 - d0;

    for (int i = tid; i < 12 * LDW; i += 256) {
        int r = i / LDW, c = i - r * LDW;
        int rg = (r >> 2) * 256 + wg * 4 + (r & 3);
        float v = 0.f;
        if (c < 414) v = W_ih[rg * 414 + c];
        else if (c >= 416 && c < 672) v = W_hh[rg * 256 + (c - 416)];
        wgl[i] = v;
    }
    for (int i = tid; i < 4 * 256; i += 256) {
        int dl_ = i >> 8, j = i & 255;
        wrol[i] = (dl_ < dc) ? W_ro[(d0 + dl_) * 256 + j] : 0.f;
    }
    if (tid < 12) {
        int rg = (tid >> 2) * 256 + wg * 4 + (tid & 3);
        bihl[tid] = b_ih[rg];
        bhhl[tid] = b_hh[rg];
    }
    if (tid < 4) brol[tid] = (tid < dc) ? b_ro[d0 + tid] : 0.f;
    hloc[tid] = 0.f;
    __syncthreads();

    const float4* A4 = (const float4*)actg;
    const int u = lane >> 4;
    const int bp = lane & 15;

    const bool have = (tid < dc * 64);
    const int dl = tid >> 6, b = tid & 63;
    const size_t gbase = (size_t)b * (SS * DD) + (d0 + dl);
    float xv_pf = 0.f, mv_pf = 0.f;
    if (have) { xv_pf = x[gbase]; mv_pf = mask[gbase]; }

    unsigned gen = 0;

    for (int t = 0; t < SS; ++t) {
        const int par = t & 1;
        const int hrow0 = V3_HBASE + par * 256;

        {
            const float* hrow = actg + hrow0 * 64;
            const int jb = wv * 64;
            float acc0 = 0.f, acc1 = 0.f, acc2 = 0.f, acc3 = 0.f;
            #pragma unroll 4
            for (int j = 0; j < 64; j += 4) {
                float a0 = hrow[(jb + j + 0) * 64 + lane];
                float a1 = hrow[(jb + j + 1) * 64 + lane];
                float a2 = hrow[(jb + j + 2) * 64 + lane];
                float a3 = hrow[(jb + j + 3) * 64 + lane];
                float4 w0 = *(const float4*)&wrol[0 * 256 + jb + j];
                float4 w1 = *(const float4*)&wrol[1 * 256 + jb + j];
                float4 w2 = *(const float4*)&wrol[2 * 256 + jb + j];
                float4 w3 = *(const float4*)&wrol[3 * 256 + jb + j];
                acc0 += a0*w0.x + a1*w0.y + a2*w0.z + a3*w0.w;
                acc1 += a0*w1.x + a1*w1.y + a2*w1.z + a3*w1.w;
                acc2 += a0*w2.x + a1*w2.y + a2*w2.z + a3*w2.w;
                acc3 += a0*w3.x + a1*w3.y + a2*w3.z + a3*w3.w;
            }
            redB[(wv * 4 + 0) * 64 + lane] = acc0;
            redB[(wv * 4 + 1) * 64 + lane] = acc1;
            redB[(wv * 4 + 2) * 64 + lane] = acc2;
            redB[(wv * 4 + 3) * 64 + lane] = acc3;
        }
        __syncthreads();
        if (have) {
            float xh = redB[(0 * 4 + dl) * 64 + b] + redB[(1 * 4 + dl) * 64 + b]
                     + redB[(2 * 4 + dl) * 64 + b] + redB[(3 * 4 + dl) * 64 + b]
                     + brol[dl];
            if (STAGE) stage[(t * DD + d0 + dl) * 64 + b] = xh;
            else       out[gbase + (size_t)t * DD] = xh;
            if (t < SS - 1) {
                float xi = (mv_pf > 0.5f) ? xv_pf : xh;
                actg[(d0 + dl) * 64 + b] = xi;
                actg[(207 + d0 + dl) * 64 + b] = mv_pf;
            }
        }
        if (t == SS - 1) break;

        if (have && t + 1 < SS - 1) {
            xv_pf = x[gbase + (size_t)(t + 1) * DD];
            mv_pf = mask[gbase + (size_t)(t + 1) * DD];
        }

        v3_gbar(flags, wg, ++gen);

        if (wv == 0)      run_range6(A4, wgl, red, u, bp, 0,   0,          168, 0);
        else if (wv == 1) run_range6(A4, wgl, red, u, bp, 168, 168,        168, 1);
        else if (wv == 2) {
            run_range6(A4, wgl, red, u, bp, 336, 336,        80,  2);
            run_range6(A4, wgl, red, u, bp, 416, hrow0,      96,  3);
        } else            run_range6(A4, wgl, red, u, bp, 512, hrow0 + 96, 160, 4);
        __syncthreads();
        {
            const int u2 = tid >> 6, b2 = tid & 63;
            float gir = red[(0*12 + 0 + u2)*64 + b2] + red[(1*12 + 0 + u2)*64 + b2]
                      + red[(2*12 + 0 + u2)*64 + b2] + bihl[0 + u2];
            float giz = red[(0*12 + 4 + u2)*64 + b2] + red[(1*12 + 4 + u2)*64 + b2]
                      + red[(2*12 + 4 + u2)*64 + b2] + bihl[4 + u2];
            float gin = red[(0*12 + 8 + u2)*64 + b2] + red[(1*12 + 8 + u2)*64 + b2]
                      + red[(2*12 + 8 + u2)*64 + b2] + bihl[8 + u2];
            float ghr = red[(3*12 + 0 + u2)*64 + b2] + red[(4*12 + 0 + u2)*64 + b2] + bhhl[0 + u2];
            float ghz = red[(3*12 + 4 + u2)*64 + b2] + red[(4*12 + 4 + u2)*64 + b2] + bhhl[4 + u2];
            float ghn = red[(3*12 + 8 + u2)*64 + b2] + red[(4*12 + 8 + u2)*64 + b2] + bhhl[8 + u2];
            float r = 1.f / (1.f + __expf(-(gir + ghr)));
            float z = 1.f / (1.f + __expf(-(giz + ghz)));
            float n = tanhf(gin + r * ghn);
            float hn = (1.f - z) * n + z * hloc[u2 * 64 + b2];
            hloc[u2 * 64 + b2] = hn;
            actg[(V3_HBASE + (par ^ 1) * 256 + wg * 4 + u2) * 64 + b2] = hn;
        }
        v3_gbar(flags, wg, ++gen);
    }
}

// ---- minimal fallback (one WG per batch) ----
__global__ __launch_bounds__(768) void rnn_fallback(
    const float* __restrict__ x, const float* __restrict__ mask,
    const float* __restrict__ W_ih, const float* __restrict__ W_hh,
    const float* __restrict__ b_ih, const float* __restrict__ b_hh,
    const float* __restrict__ W_ro, const float* __restrict__ b_ro,
    float* __restrict__ out)
{
    const int b = blockIdx.x, tid = threadIdx.x;
    __shared__ float h[HH];
    __shared__ float hnew[HH];
    __shared__ float xin[414 + 2];
    __shared__ float gi[768];
    __shared__ float gh[768];
    __shared__ float xhat[DD];
    const float bih = b_ih[tid], bhh = b_hh[tid];
    const float bro = (tid < DD) ? b_ro[tid] : 0.f;
    if (tid < HH) h[tid] = 0.f;
    if (tid < DD) xhat[tid] = bro;
    __syncthreads();
    const float* xb = x + (size_t)b * SS * DD;
    const float* mb = mask + (size_t)b * SS * DD;
    float* ob = out + (size_t)b * SS * DD;
    for (int t = 0; t < SS; ++t) {
        if (tid < DD) ob[t * DD + tid] = xhat[tid];
        if (t == SS - 1) break;
        if (tid < DD) {
            float m = mb[t * DD + tid], xv = xb[t * DD + tid];
            xin[tid] = (m > 0.5f) ? xv : xhat[tid];
            xin[DD + tid] = m;
        }
        __syncthreads();
        float accI = bih, accH = bhh;
        const float* wi = W_ih + (size_t)tid * 414;
        for (int k = 0; k < 414; ++k) accI += wi[k] * xin[k];
        const float* wh = W_hh + (size_t)tid * HH;
        for (int k = 0; k < HH; ++k) accH += wh[k] * h[k];
        gi[tid] = accI; gh[tid] = accH;
        __syncthreads();
        if (tid < HH) {
            float r = 1.f / (1.f + __expf(-(gi[tid] + gh[tid])));
            float z = 1.f / (1.f + __expf(-(gi[HH + tid] + gh[HH + tid])));
            float n = tanhf(gi[2 * HH + tid] + r * gh[2 * HH + tid]);
            hnew[tid] = (1.f - z) * n + z * h[tid];
        }
        __syncthreads();
        if (tid < DD) {
            float acc = bro;
            const float* wr = W_ro + (size_t)tid * HH;
            for (int k = 0; k < HH; ++k) acc += wr[k] * hnew[k];
            xhat[tid] = acc;
        }
        if (tid < HH) h[tid] = hnew[tid];
        __syncthreads();
    }
}

extern "C" void kernel_launch(void* const* d_in, const int* in_sizes, int n_in,
                              void* d_out, int out_size, void* d_ws, size_t ws_size,
                              hipStream_t stream) {
    const float* x    = (const float*)d_in[0];
    const float* mask = (const float*)d_in[1];
    const float* W_ih = (const float*)d_in[2];
    const float* W_hh = (const float*)d_in[3];
    const float* b_ih = (const float*)d_in[4];
    const float* b_hh = (const float*)d_in[5];
    const float* W_ro = (const float*)d_in[6];
    const float* b_ro = (const float*)d_in[7];
    float* out = (float*)d_out;
    float* ws  = (float*)d_ws;

    if (ws_size >= WS_NEED6) {
        hipLaunchKernelGGL(rnn_init6, dim3(64), dim3(256), 0, stream, ws);
        hipLaunchKernelGGL(rnn_persist18, dim3(NWG), dim3(512), 0, stream,
                           x, mask, W_ih, W_hh, b_ih, b_hh, W_ro, b_ro, ws, out);
        hipLaunchKernelGGL(out_transpose, dim3(SS), dim3(256), 0, stream,
                           ws + BUF_FLOATS + FLAG_U32, out);
    } else if (ws_size >= V3_WS_FULL) {
        hipLaunchKernelGGL(v3_init, dim3(32), dim3(256), 0, stream, ws);
        hipLaunchKernelGGL((v3_persist<true>), dim3(NWG), dim3(256), 0, stream,
                           x, mask, W_ih, W_hh, b_ih, b_hh, W_ro, b_ro, ws, out);
        hipLaunchKernelGGL(out_transpose, dim3(SS), dim3(256), 0, stream,
                           ws + V3_ACT + V3_FLAGS, out);
    } else if (ws_size >= V3_WS_SMALL) {
        hipLaunchKernelGGL(v3_init, dim3(32), dim3(256), 0, stream, ws);
        hipLaunchKernelGGL((v3_persist<false>), dim3(NWG), dim3(256), 0, stream,
                           x, mask, W_ih, W_hh, b_ih, b_hh, W_ro, b_ro, ws, out);
    } else {
        hipLaunchKernelGGL(rnn_fallback, dim3(BB), dim3(768), 0, stream,
                           x, mask, W_ih, W_hh, b_ih, b_hh, W_ro, b_ro, out);
    }
}

// Round 14
// 4932.056 us; speedup vs baseline: 1.2254x; 1.2015x over previous
//
#include <hip/hip_runtime.h>
#include <math.h>

#define BB 64
#define SS 512
#define DD 207
#define HH 256
#define NWG 64
#define LDW 676   // wgl row stride (%32==4 -> staggered banks)
#define ROW 260   // wrol row stride
#define AG __HIP_MEMORY_SCOPE_AGENT

// ================= v13 (RESTORED CHAMPION, 4893 us) ==========================
// 64 WGs x 512 threads (8 waves, 2/SIMD). Step-slot rotation, sc1 publishes,
// virgin cached reads, monotone flags, 2 barriers/step. Fused PhaseB+gh pass:
// one float4 pass over h_t accumulates gate rows {u,4+u,8+u} AND readout row
// u from the same load stream. Output store deferred past arr1 flag.
// Ten structural variants tested (v9,v10,v11,v12,v14,v15,v17,v18 + waves/
// grouping): all neutral or worse. Remaining 9.6 us/step = 511-step serial
// chain: 2 cross-XCD L3 exchanges + LDS-pinned 2-wave/SIMD GEMV latency.
#define SROWS 672
#define HOFF  416
#define SLOT  (SROWS * 64)
#define BUF_FLOATS ((size_t)SS * SLOT)
#define FLAG_U32 (64 * 32)
#define STAGE_FLOATS ((size_t)SS * DD * 64)
#define WS_NEED6 ((BUF_FLOATS + FLAG_U32 + STAGE_FLOATS) * sizeof(float))

// ---- v3 fallback layout (round-3 proven path) ----
#define V3_AROWS 928
#define V3_HBASE 416
#define V3_ACT (V3_AROWS * 64)
#define V3_FLAGS (64 * 32)
#define V3_WS_SMALL ((size_t)(V3_ACT + V3_FLAGS) * sizeof(float))
#define V3_WS_FULL  ((size_t)(V3_ACT + V3_FLAGS + STAGE_FLOATS) * sizeof(float))

__device__ __forceinline__ void ast4(float* p, float v) {
    union { float f; unsigned u; } c; c.f = v;
    __hip_atomic_store((unsigned*)p, c.u, __ATOMIC_RELAXED, AG);
}

// 12-row (3 gates x unit u) GEMV partial, NORMAL float4 loads (round-3 shape).
// gr0 = global float4-row base (t*672 + local row), wc0 = weight col base.
__device__ __forceinline__ void run_range6(
    const float4* __restrict__ A4, const float* __restrict__ wgl,
    float* __restrict__ red, int u, int bp, int wc0, int gr0, int len, int slot)
{
    float4 c0 = make_float4(0.f, 0.f, 0.f, 0.f);
    float4 c1 = c0, c2 = c0;
    #pragma unroll 4
    for (int k = 0; k < len; k += 4) {
        float4 a0 = A4[(gr0 + k + 0) * 16 + bp];
        float4 a1 = A4[(gr0 + k + 1) * 16 + bp];
        float4 a2 = A4[(gr0 + k + 2) * 16 + bp];
        float4 a3 = A4[(gr0 + k + 3) * 16 + bp];
        float4 w0 = *(const float4*)&wgl[(0 + u) * LDW + wc0 + k];
        float4 w1 = *(const float4*)&wgl[(4 + u) * LDW + wc0 + k];
        float4 w2 = *(const float4*)&wgl[(8 + u) * LDW + wc0 + k];
        c0.x += a0.x*w0.x + a1.x*w0.y + a2.x*w0.z + a3.x*w0.w;
        c0.y += a0.y*w0.x + a1.y*w0.y + a2.y*w0.z + a3.y*w0.w;
        c0.z += a0.z*w0.x + a1.z*w0.y + a2.z*w0.z + a3.z*w0.w;
        c0.w += a0.w*w0.x + a1.w*w0.y + a2.w*w0.z + a3.w*w0.w;
        c1.x += a0.x*w1.x + a1.x*w1.y + a2.x*w1.z + a3.x*w1.w;
        c1.y += a0.y*w1.x + a1.y*w1.y + a2.y*w1.z + a3.y*w1.w;
        c1.z += a0.z*w1.x + a1.z*w1.y + a2.z*w1.z + a3.z*w1.w;
        c1.w += a0.w*w1.x + a1.w*w1.y + a2.w*w1.z + a3.w*w1.w;
        c2.x += a0.x*w2.x + a1.x*w2.y + a2.x*w2.z + a3.x*w2.w;
        c2.y += a0.y*w2.x + a1.y*w2.y + a2.y*w2.z + a3.y*w2.w;
        c2.z += a0.z*w2.x + a1.z*w2.y + a2.z*w2.z + a3.z*w2.w;
        c2.w += a0.w*w2.x + a1.w*w2.y + a2.w*w2.z + a3.w*w2.w;
    }
    float4* R4 = (float4*)red;
    R4[(slot * 12 + 0 + u) * 16 + bp] = c0;
    R4[(slot * 12 + 4 + u) * 16 + bp] = c1;
    R4[(slot * 12 + 8 + u) * 16 + bp] = c2;
}

__global__ __launch_bounds__(256) void rnn_init6(float* __restrict__ ws) {
    int i = blockIdx.x * blockDim.x + threadIdx.x;
    // zero slot-0 h rows (h_0 = 0)
    for (int idx = i; idx < HH * 64; idx += gridDim.x * blockDim.x)
        ws[HOFF * 64 + idx] = 0.f;
    unsigned* fl = (unsigned*)(ws + BUF_FLOATS);
    for (int idx = i; idx < FLAG_U32; idx += gridDim.x * blockDim.x)
        fl[idx] = 0u;
}

__global__ __launch_bounds__(512) void rnn_persist13(
    const float* __restrict__ x, const float* __restrict__ mask,
    const float* __restrict__ W_ih, const float* __restrict__ W_hh,
    const float* __restrict__ b_ih, const float* __restrict__ b_hh,
    const float* __restrict__ W_ro, const float* __restrict__ b_ro,
    float* __restrict__ ws, float* __restrict__ out)
{
    const int wg = blockIdx.x;
    const int tid = threadIdx.x;
    const int lane = tid & 63;
    const int wv = tid >> 6;          // 0..7

    float* buf = ws;
    unsigned* flags = (unsigned*)(ws + BUF_FLOATS);
    float* stage = ws + BUF_FLOATS + FLAG_U32;

    __shared__ float wgl[12 * LDW];      // 12 gate rows x 676 (cols 414/415 = 0)
    __shared__ float wrol[4 * ROW];      // up to 4 readout rows
    __shared__ float red[16 * 12 * 64];  // slots 0-7 xin partials, 8-15 gh
    __shared__ float redB[32 * 64];      // readout partials (8 waves x 4 rows)
    __shared__ float hloc[4 * 64];       // own hidden units
    __shared__ float bihl[12], bhhl[12], brol[4];

    const int d0 = (207 * wg) / NWG;
    const int d1 = (207 * (wg + 1)) / NWG;
    const int dc = d1 - d0;

    for (int i = tid; i < 12 * LDW; i += 512) {
        int r = i / LDW, c = i - r * LDW;
        int rg = (r >> 2) * 256 + wg * 4 + (r & 3);
        float v = 0.f;
        if (c < 414) v = W_ih[rg * 414 + c];
        else if (c >= 416 && c < 672) v = W_hh[rg * 256 + (c - 416)];
        wgl[i] = v;
    }
    for (int i = tid; i < 4 * 256; i += 512) {
        int dl_ = i >> 8, j = i & 255;
        wrol[dl_ * ROW + j] = (dl_ < dc) ? W_ro[(d0 + dl_) * 256 + j] : 0.f;
    }
    if (tid < 12) {
        int rg = (tid >> 2) * 256 + wg * 4 + (tid & 3);
        bihl[tid] = b_ih[rg];
        bhhl[tid] = b_hh[rg];
    }
    if (tid < 4) brol[tid] = (tid < dc) ? b_ro[d0 + tid] : 0.f;
    if (tid < 256) hloc[tid] = 0.f;
    __syncthreads();

    const float4* A4 = (const float4*)buf;
    const int u  = lane >> 4;
    const int bp = lane & 15;

    const bool have = (tid < dc * 64);
    const int dl = tid >> 6, b = tid & 63;
    const size_t gbase = (size_t)b * (SS * DD) + (d0 + dl);
    float xv_pf = 0.f, mv_pf = 0.f;
    if (have) { xv_pf = x[gbase]; mv_pf = mask[gbase]; }

    unsigned gen = 0;

    for (int t = 0; t < SS; ++t) {
        const int sbase = t * SROWS;        // this step's slot (row units)

        // ---- Fused Phase B + gh: ONE pass over h_t (float4, virgin reads) ----
        // Thread (wv,u,bp): cols jb..jb+32, gate rows {u,4+u,8+u} -> red slot
        // 8+wv, readout row u -> redB. Same loads serve both.
        {
            const int jb = wv * 32;
            const int gr0 = sbase + HOFF + jb;     // h rows (float4 rows)
            const int wc0 = 416 + jb;              // gate weight cols
            float4 c0 = make_float4(0.f, 0.f, 0.f, 0.f);
            float4 c1 = c0, c2 = c0, cR = c0;
            #pragma unroll 4
            for (int k = 0; k < 32; k += 4) {
                float4 a0 = A4[(gr0 + k + 0) * 16 + bp];
                float4 a1 = A4[(gr0 + k + 1) * 16 + bp];
                float4 a2 = A4[(gr0 + k + 2) * 16 + bp];
                float4 a3 = A4[(gr0 + k + 3) * 16 + bp];
                float4 w0 = *(const float4*)&wgl[(0 + u) * LDW + wc0 + k];
                float4 w1 = *(const float4*)&wgl[(4 + u) * LDW + wc0 + k];
                float4 w2 = *(const float4*)&wgl[(8 + u) * LDW + wc0 + k];
                float4 wR = *(const float4*)&wrol[u * ROW + jb + k];
                c0.x += a0.x*w0.x + a1.x*w0.y + a2.x*w0.z + a3.x*w0.w;
                c0.y += a0.y*w0.x + a1.y*w0.y + a2.y*w0.z + a3.y*w0.w;
                c0.z += a0.z*w0.x + a1.z*w0.y + a2.z*w0.z + a3.z*w0.w;
                c0.w += a0.w*w0.x + a1.w*w0.y + a2.w*w0.z + a3.w*w0.w;
                c1.x += a0.x*w1.x + a1.x*w1.y + a2.x*w1.z + a3.x*w1.w;
                c1.y += a0.y*w1.x + a1.y*w1.y + a2.y*w1.z + a3.y*w1.w;
                c1.z += a0.z*w1.x + a1.z*w1.y + a2.z*w1.z + a3.z*w1.w;
                c1.w += a0.w*w1.x + a1.w*w1.y + a2.w*w1.z + a3.w*w1.w;
                c2.x += a0.x*w2.x + a1.x*w2.y + a2.x*w2.z + a3.x*w2.w;
                c2.y += a0.y*w2.x + a1.y*w2.y + a2.y*w2.z + a3.y*w2.w;
                c2.z += a0.z*w2.x + a1.z*w2.y + a2.z*w2.z + a3.z*w2.w;
                c2.w += a0.w*w2.x + a1.w*w2.y + a2.w*w2.z + a3.w*w2.w;
                cR.x += a0.x*wR.x + a1.x*wR.y + a2.x*wR.z + a3.x*wR.w;
                cR.y += a0.y*wR.x + a1.y*wR.y + a2.y*wR.z + a3.y*wR.w;
                cR.z += a0.z*wR.x + a1.z*wR.y + a2.z*wR.z + a3.z*wR.w;
                cR.w += a0.w*wR.x + a1.w*wR.y + a2.w*wR.z + a3.w*wR.w;
            }
            float4* R4 = (float4*)red;
            R4[((8 + wv) * 12 + 0 + u) * 16 + bp] = c0;
            R4[((8 + wv) * 12 + 4 + u) * 16 + bp] = c1;
            R4[((8 + wv) * 12 + 8 + u) * 16 + bp] = c2;
            float4* RB4 = (float4*)redB;
            RB4[(wv * 4 + u) * 16 + bp] = cR;
        }
        __syncthreads();

        float xh = 0.f;
        if (have) {
            xh = brol[dl];
            #pragma unroll
            for (int g = 0; g < 8; ++g)
                xh += redB[(g * 4 + dl) * 64 + b];
            if (t < SS - 1) {
                float xi = (mv_pf > 0.5f) ? xv_pf : xh;
                ast4(&buf[(size_t)(sbase + d0 + dl) * 64 + b], xi);        // sc1
                ast4(&buf[(size_t)(sbase + 207 + d0 + dl) * 64 + b], mv_pf);
            }
        }
        if (t == SS - 1) {
            if (have) stage[(t * DD + d0 + dl) * 64 + b] = xh;
            break;
        }

        // ---- arrive 1: xin_t published (drain = 2 ast4 only) ----
        ++gen;
        asm volatile("s_waitcnt vmcnt(0)" ::: "memory");
        __syncthreads();
        if (tid == 0)
            __hip_atomic_store(&flags[wg * 32], gen, __ATOMIC_RELAXED, AG);

        // deferred output store (out of the drain set)
        if (have) stage[(t * DD + d0 + dl) * 64 + b] = xh;

        // ---- wait 1 ----
        if (tid < 64) {
            unsigned* f = &flags[tid * 32];
            while (__hip_atomic_load(f, __ATOMIC_RELAXED, AG) < gen) {}
        }
        __syncthreads();

        // ---- gate xin GEMV: 8 waves x 52 rows (virgin cached reads) ----
        run_range6(A4, wgl, red, u, bp, wv * 52, sbase + wv * 52, 52, wv);
        __syncthreads();

        // ---- combine + gates + publish h_{t+1} into slot t+1 (sc1) ----
        if (tid < 256) {
            const int u2 = tid >> 6, b2 = tid & 63;
            float gir = bihl[0 + u2], giz = bihl[4 + u2], gin = bihl[8 + u2];
            float ghr = bhhl[0 + u2], ghz = bhhl[4 + u2], ghn = bhhl[8 + u2];
            #pragma unroll
            for (int s = 0; s < 8; ++s) {
                gir += red[(s * 12 + 0 + u2) * 64 + b2];
                giz += red[(s * 12 + 4 + u2) * 64 + b2];
                gin += red[(s * 12 + 8 + u2) * 64 + b2];
                ghr += red[((8 + s) * 12 + 0 + u2) * 64 + b2];
                ghz += red[((8 + s) * 12 + 4 + u2) * 64 + b2];
                ghn += red[((8 + s) * 12 + 8 + u2) * 64 + b2];
            }
            float r = 1.f / (1.f + __expf(-(gir + ghr)));
            float z = 1.f / (1.f + __expf(-(giz + ghz)));
            float n = tanhf(gin + r * ghn);
            float hn = (1.f - z) * n + z * hloc[u2 * 64 + b2];
            hloc[u2 * 64 + b2] = hn;
            ast4(&buf[(size_t)((t + 1) * SROWS + HOFF + wg * 4 + u2) * 64 + b2], hn);
        }

        // ---- arrive 2: h_{t+1} published ----
        ++gen;
        asm volatile("s_waitcnt vmcnt(0)" ::: "memory");
        __syncthreads();
        if (tid == 0)
            __hip_atomic_store(&flags[wg * 32], gen, __ATOMIC_RELAXED, AG);

        // ---- overlap: next x/mask prefetch ----
        if (have && t + 1 < SS - 1) {
            xv_pf = x[gbase + (size_t)(t + 1) * DD];
            mv_pf = mask[gbase + (size_t)(t + 1) * DD];
        }

        // ---- wait 2 ----
        if (tid < 64) {
            unsigned* f = &flags[tid * 32];
            while (__hip_atomic_load(f, __ATOMIC_RELAXED, AG) < gen) {}
        }
        __syncthreads();
    }
}

// epilogue: stage[t][d][b] -> out[b][t][d]
__global__ __launch_bounds__(256) void out_transpose(
    const float* __restrict__ stage, float* __restrict__ out)
{
    __shared__ float lds[DD * 65];
    const int t = blockIdx.x;
    const float* st = stage + (size_t)t * DD * 64;
    for (int i = threadIdx.x; i < DD * 64; i += 256) {
        int d = i >> 6, b = i & 63;
        lds[d * 65 + b] = st[i];
    }
    __syncthreads();
    for (int i = threadIdx.x; i < DD * 64; i += 256) {
        int b = i / DD, d = i - b * DD;
        out[(size_t)b * (SS * DD) + (size_t)t * DD + d] = lds[d * 65 + b];
    }
}

// ================= v3 middle fallback (round-3 proven, 8.1 ms) =================
__device__ __forceinline__ void v3_gbar(unsigned* flags, int wg, unsigned g) {
    __syncthreads();
    if (threadIdx.x < 64) {
        if (threadIdx.x == 0) {
            __builtin_amdgcn_fence(__ATOMIC_RELEASE, "agent");
            __hip_atomic_store(&flags[wg * 32], g, __ATOMIC_RELAXED, AG);
        }
        unsigned* f = &flags[threadIdx.x * 32];
        while (__hip_atomic_load(f, __ATOMIC_RELAXED, AG) < g) { }
        __builtin_amdgcn_fence(__ATOMIC_ACQUIRE, "agent");
    }
    __syncthreads();
}

__global__ __launch_bounds__(256) void v3_init(float* __restrict__ ws) {
    int i = blockIdx.x * blockDim.x + threadIdx.x;
    const int nz = (672 - 414) * 64;
    for (int idx = i; idx < nz; idx += gridDim.x * blockDim.x)
        ws[414 * 64 + idx] = 0.f;
    for (int idx = i; idx < V3_FLAGS; idx += gridDim.x * blockDim.x)
        ((unsigned*)(ws + V3_ACT))[idx] = 0u;
}

template<bool STAGE>
__global__ __launch_bounds__(256) void v3_persist(
    const float* __restrict__ x, const float* __restrict__ mask,
    const float* __restrict__ W_ih, const float* __restrict__ W_hh,
    const float* __restrict__ b_ih, const float* __restrict__ b_hh,
    const float* __restrict__ W_ro, const float* __restrict__ b_ro,
    float* __restrict__ ws, float* __restrict__ out)
{
    const int wg = blockIdx.x;
    const int tid = threadIdx.x;
    const int lane = tid & 63;
    const int wv = tid >> 6;

    float* actg = ws;
    unsigned* flags = (unsigned*)(ws + V3_ACT);
    float* stage = ws + V3_ACT + V3_FLAGS;

    __shared__ float wgl[12 * LDW];
    __shared__ float wrol[4 * 256];
    __shared__ float red[5 * 12 * 64];
    __shared__ float redB[16 * 64];
    __shared__ float hloc[4 * 64];
    __shared__ float bihl[12], bhhl[12], brol[4];

    const int d0 = (207 * wg) / NWG;
    const int d1 = (207 * (wg + 1)) / NWG;
    const int dc = d1 - d0;

    for (int i = tid; i < 12 * LDW; i += 256) {
        int r = i / LDW, c = i - r * LDW;
        int rg = (r >> 2) * 256 + wg * 4 + (r & 3);
        float v = 0.f;
        if (c < 414) v = W_ih[rg * 414 + c];
        else if (c >= 416 && c < 672) v = W_hh[rg * 256 + (c - 416)];
        wgl[i] = v;
    }
    for (int i = tid; i < 4 * 256; i += 256) {
        int dl_ = i >> 8, j = i & 255;
        wrol[i] = (dl_ < dc) ? W_ro[(d0 + dl_) * 256 + j] : 0.f;
    }
    if (tid < 12) {
        int rg = (tid >> 2) * 256 + wg * 4 + (tid & 3);
        bihl[tid] = b_ih[rg];
        bhhl[tid] = b_hh[rg];
    }
    if (tid < 4) brol[tid] = (tid < dc) ? b_ro[d0 + tid] : 0.f;
    hloc[tid] = 0.f;
    __syncthreads();

    const float4* A4 = (const float4*)actg;
    const int u = lane >> 4;
    const int bp = lane & 15;

    const bool have = (tid < dc * 64);
    const int dl = tid >> 6, b = tid & 63;
    const size_t gbase = (size_t)b * (SS * DD) + (d0 + dl);
    float xv_pf = 0.f, mv_pf = 0.f;
    if (have) { xv_pf = x[gbase]; mv_pf = mask[gbase]; }

    unsigned gen = 0;

    for (int t = 0; t < SS; ++t) {
        const int par = t & 1;
        const int hrow0 = V3_HBASE + par * 256;

        {
            const float* hrow = actg + hrow0 * 64;
            const int jb = wv * 64;
            float acc0 = 0.f, acc1 = 0.f, acc2 = 0.f, acc3 = 0.f;
            #pragma unroll 4
            for (int j = 0; j < 64; j += 4) {
                float a0 = hrow[(jb + j + 0) * 64 + lane];
                float a1 = hrow[(jb + j + 1) * 64 + lane];
                float a2 = hrow[(jb + j + 2) * 64 + lane];
                float a3 = hrow[(jb + j + 3) * 64 + lane];
                float4 w0 = *(const float4*)&wrol[0 * 256 + jb + j];
                float4 w1 = *(const float4*)&wrol[1 * 256 + jb + j];
                float4 w2 = *(const float4*)&wrol[2 * 256 + jb + j];
                float4 w3 = *(const float4*)&wrol[3 * 256 + jb + j];
                acc0 += a0*w0.x + a1*w0.y + a2*w0.z + a3*w0.w;
                acc1 += a0*w1.x + a1*w1.y + a2*w1.z + a3*w1.w;
                acc2 += a0*w2.x + a1*w2.y + a2*w2.z + a3*w2.w;
                acc3 += a0*w3.x + a1*w3.y + a2*w3.z + a3*w3.w;
            }
            redB[(wv * 4 + 0) * 64 + lane] = acc0;
            redB[(wv * 4 + 1) * 64 + lane] = acc1;
            redB[(wv * 4 + 2) * 64 + lane] = acc2;
            redB[(wv * 4 + 3) * 64 + lane] = acc3;
        }
        __syncthreads();
        if (have) {
            float xh = redB[(0 * 4 + dl) * 64 + b] + redB[(1 * 4 + dl) * 64 + b]
                     + redB[(2 * 4 + dl) * 64 + b] + redB[(3 * 4 + dl) * 64 + b]
                     + brol[dl];
            if (STAGE) stage[(t * DD + d0 + dl) * 64 + b] = xh;
            else       out[gbase + (size_t)t * DD] = xh;
            if (t < SS - 1) {
                float xi = (mv_pf > 0.5f) ? xv_pf : xh;
                actg[(d0 + dl) * 64 + b] = xi;
                actg[(207 + d0 + dl) * 64 + b] = mv_pf;
            }
        }
        if (t == SS - 1) break;

        if (have && t + 1 < SS - 1) {
            xv_pf = x[gbase + (size_t)(t + 1) * DD];
            mv_pf = mask[gbase + (size_t)(t + 1) * DD];
        }

        v3_gbar(flags, wg, ++gen);

        if (wv == 0)      run_range6(A4, wgl, red, u, bp, 0,   0,          168, 0);
        else if (wv == 1) run_range6(A4, wgl, red, u, bp, 168, 168,        168, 1);
        else if (wv == 2) {
            run_range6(A4, wgl, red, u, bp, 336, 336,        80,  2);
            run_range6(A4, wgl, red, u, bp, 416, hrow0,      96,  3);
        } else            run_range6(A4, wgl, red, u, bp, 512, hrow0 + 96, 160, 4);
        __syncthreads();
        {
            const int u2 = tid >> 6, b2 = tid & 63;
            float gir = red[(0*12 + 0 + u2)*64 + b2] + red[(1*12 + 0 + u2)*64 + b2]
                      + red[(2*12 + 0 + u2)*64 + b2] + bihl[0 + u2];
            float giz = red[(0*12 + 4 + u2)*64 + b2] + red[(1*12 + 4 + u2)*64 + b2]
                      + red[(2*12 + 4 + u2)*64 + b2] + bihl[4 + u2];
            float gin = red[(0*12 + 8 + u2)*64 + b2] + red[(1*12 + 8 + u2)*64 + b2]
                      + red[(2*12 + 8 + u2)*64 + b2] + bihl[8 + u2];
            float ghr = red[(3*12 + 0 + u2)*64 + b2] + red[(4*12 + 0 + u2)*64 + b2] + bhhl[0 + u2];
            float ghz = red[(3*12 + 4 + u2)*64 + b2] + red[(4*12 + 4 + u2)*64 + b2] + bhhl[4 + u2];
            float ghn = red[(3*12 + 8 + u2)*64 + b2] + red[(4*12 + 8 + u2)*64 + b2] + bhhl[8 + u2];
            float r = 1.f / (1.f + __expf(-(gir + ghr)));
            float z = 1.f / (1.f + __expf(-(giz + ghz)));
            float n = tanhf(gin + r * ghn);
            float hn = (1.f - z) * n + z * hloc[u2 * 64 + b2];
            hloc[u2 * 64 + b2] = hn;
            actg[(V3_HBASE + (par ^ 1) * 256 + wg * 4 + u2) * 64 + b2] = hn;
        }
        v3_gbar(flags, wg, ++gen);
    }
}

// ---- minimal fallback (one WG per batch) ----
__global__ __launch_bounds__(768) void rnn_fallback(
    const float* __restrict__ x, const float* __restrict__ mask,
    const float* __restrict__ W_ih, const float* __restrict__ W_hh,
    const float* __restrict__ b_ih, const float* __restrict__ b_hh,
    const float* __restrict__ W_ro, const float* __restrict__ b_ro,
    float* __restrict__ out)
{
    const int b = blockIdx.x, tid = threadIdx.x;
    __shared__ float h[HH];
    __shared__ float hnew[HH];
    __shared__ float xin[414 + 2];
    __shared__ float gi[768];
    __shared__ float gh[768];
    __shared__ float xhat[DD];
    const float bih = b_ih[tid], bhh = b_hh[tid];
    const float bro = (tid < DD) ? b_ro[tid] : 0.f;
    if (tid < HH) h[tid] = 0.f;
    if (tid < DD) xhat[tid] = bro;
    __syncthreads();
    const float* xb = x + (size_t)b * SS * DD;
    const float* mb = mask + (size_t)b * SS * DD;
    float* ob = out + (size_t)b * SS * DD;
    for (int t = 0; t < SS; ++t) {
        if (tid < DD) ob[t * DD + tid] = xhat[tid];
        if (t == SS - 1) break;
        if (tid < DD) {
            float m = mb[t * DD + tid], xv = xb[t * DD + tid];
            xin[tid] = (m > 0.5f) ? xv : xhat[tid];
            xin[DD + tid] = m;
        }
        __syncthreads();
        float accI = bih, accH = bhh;
        const float* wi = W_ih + (size_t)tid * 414;
        for (int k = 0; k < 414; ++k) accI += wi[k] * xin[k];
        const float* wh = W_hh + (size_t)tid * HH;
        for (int k = 0; k < HH; ++k) accH += wh[k] * h[k];
        gi[tid] = accI; gh[tid] = accH;
        __syncthreads();
        if (tid < HH) {
            float r = 1.f / (1.f + __expf(-(gi[tid] + gh[tid])));
            float z = 1.f / (1.f + __expf(-(gi[HH + tid] + gh[HH + tid])));
            float n = tanhf(gi[2 * HH + tid] + r * gh[2 * HH + tid]);
            hnew[tid] = (1.f - z) * n + z * h[tid];
        }
        __syncthreads();
        if (tid < DD) {
            float acc = bro;
            const float* wr = W_ro + (size_t)tid * HH;
            for (int k = 0; k < HH; ++k) acc += wr[k] * hnew[k];
            xhat[tid] = acc;
        }
        if (tid < HH) h[tid] = hnew[tid];
        __syncthreads();
    }
}

extern "C" void kernel_launch(void* const* d_in, const int* in_sizes, int n_in,
                              void* d_out, int out_size, void* d_ws, size_t ws_size,
                              hipStream_t stream) {
    const float* x    = (const float*)d_in[0];
    const float* mask = (const float*)d_in[1];
    const float* W_ih = (const float*)d_in[2];
    const float* W_hh = (const float*)d_in[3];
    const float* b_ih = (const float*)d_in[4];
    const float* b_hh = (const float*)d_in[5];
    const float* W_ro = (const float*)d_in[6];
    const float* b_ro = (const float*)d_in[7];
    float* out = (float*)d_out;
    float* ws  = (float*)d_ws;

    if (ws_size >= WS_NEED6) {
        hipLaunchKernelGGL(rnn_init6, dim3(64), dim3(256), 0, stream, ws);
        hipLaunchKernelGGL(rnn_persist13, dim3(NWG), dim3(512), 0, stream,
                           x, mask, W_ih, W_hh, b_ih, b_hh, W_ro, b_ro, ws, out);
        hipLaunchKernelGGL(out_transpose, dim3(SS), dim3(256), 0, stream,
                           ws + BUF_FLOATS + FLAG_U32, out);
    } else if (ws_size >= V3_WS_FULL) {
        hipLaunchKernelGGL(v3_init, dim3(32), dim3(256), 0, stream, ws);
        hipLaunchKernelGGL((v3_persist<true>), dim3(NWG), dim3(256), 0, stream,
                           x, mask, W_ih, W_hh, b_ih, b_hh, W_ro, b_ro, ws, out);
        hipLaunchKernelGGL(out_transpose, dim3(SS), dim3(256), 0, stream,
                           ws + V3_ACT + V3_FLAGS, out);
    } else if (ws_size >= V3_WS_SMALL) {
        hipLaunchKernelGGL(v3_init, dim3(32), dim3(256), 0, stream, ws);
        hipLaunchKernelGGL((v3_persist<false>), dim3(NWG), dim3(256), 0, stream,
                           x, mask, W_ih, W_hh, b_ih, b_hh, W_ro, b_ro, ws, out);
    } else {
        hipLaunchKernelGGL(rnn_fallback, dim3(BB), dim3(768), 0, stream,
                           x, mask, W_ih, W_hh, b_ih, b_hh, W_ro, b_ro, out);
    }
}